// Round 3
// baseline (575.522 us; speedup 1.0000x reference)
//
#include <hip/hip_runtime.h>

typedef unsigned short u16;
typedef unsigned int   u32;

#define T_TOK 2048
#define DIM   2048
#define FDIM  1408
#define NEXP  8
#define SLOTS 4224   // 4096 + 128 tail headroom

typedef __bf16 bf16x8 __attribute__((ext_vector_type(8)));
typedef float  f32x4  __attribute__((ext_vector_type(4)));

union B16 { uint4 u; bf16x8 v; };

__device__ __forceinline__ u16 f2bf(float f) {
  union { float f; u32 u; } c; c.f = f;
  u32 u = c.u;
  u += 0x7FFFu + ((u >> 16) & 1u);   // round-to-nearest-even
  return (u16)(u >> 16);
}
__device__ __forceinline__ float bf2f(u16 h) {
  union { u32 u; float f; } c; c.u = (u32)h << 16; return c.f;
}

// async global->LDS, 16B per lane; lds base wave-uniform, lane i lands at base + i*16
__device__ __forceinline__ void gld_lds16(const void* g, void* l) {
  __builtin_amdgcn_global_load_lds(
      (const __attribute__((address_space(1))) unsigned int*)g,
      (__attribute__((address_space(3))) unsigned int*)l, 16, 0, 0);
}

// ---------------- weight cvt fp32->bf16 + transpose [K][N] -> [N][K] ----------------
__global__ __launch_bounds__(256) void cvt_transpose(
    const float* __restrict__ Wg, const float* __restrict__ Wu, const float* __restrict__ Wd,
    u16* __restrict__ WgT, u16* __restrict__ WuT, u16* __restrict__ WdT)
{
  const int z = blockIdx.z;
  const int tensor = z >> 3;
  const int e = z & 7;
  const int Kt = (tensor == 2) ? FDIM : DIM;
  const int Nt = (tensor == 2) ? DIM : FDIM;
  const float* src;
  u16* dst;
  if (tensor == 0)      { src = Wg + (size_t)e * DIM * FDIM; dst = WgT + (size_t)e * DIM * FDIM; }
  else if (tensor == 1) { src = Wu + (size_t)e * DIM * FDIM; dst = WuT + (size_t)e * DIM * FDIM; }
  else                  { src = Wd + (size_t)e * DIM * FDIM; dst = WdT + (size_t)e * DIM * FDIM; }
  const int k0 = blockIdx.y * 64, n0 = blockIdx.x * 64;
  if (k0 >= Kt || n0 >= Nt) return;

  __shared__ u16 tile[64][68];   // +4 pad
  const int tid = threadIdx.x;
  #pragma unroll
  for (int p = 0; p < 4; ++p) {                      // coalesced fp32 reads, 16 k-rows/pass
    int k = p * 16 + (tid >> 4);
    int n = (tid & 15) * 4;
    float4 v = *(const float4*)(src + (size_t)(k0 + k) * Nt + n0 + n);
    uint2 o;
    o.x = (u32)f2bf(v.x) | ((u32)f2bf(v.y) << 16);
    o.y = (u32)f2bf(v.z) | ((u32)f2bf(v.w) << 16);
    *(uint2*)(&tile[k][n]) = o;
  }
  __syncthreads();
  // write phase: 16B per lane, 8 rows x 128B contiguous per wave
  #pragma unroll
  for (int p = 0; p < 2; ++p) {
    int n  = p * 32 + (tid >> 3);
    int kc = (tid & 7) * 8;
    u16 r[8];
    #pragma unroll
    for (int j = 0; j < 8; ++j) r[j] = tile[kc + j][n];
    uint4 o;
    o.x = (u32)r[0] | ((u32)r[1] << 16);
    o.y = (u32)r[2] | ((u32)r[3] << 16);
    o.z = (u32)r[4] | ((u32)r[5] << 16);
    o.w = (u32)r[6] | ((u32)r[7] << 16);
    *(uint4*)(dst + (size_t)(n0 + n) * Kt + k0 + kc) = o;
  }
}

// ---------------- router: fp32 logits, softmax top-2 renormalized ----------------
__global__ __launch_bounds__(256) void router_kernel(
    const float* __restrict__ x, const float* __restrict__ gate_w,
    int* __restrict__ sel, float* __restrict__ wgt, int* __restrict__ counts)
{
  const int t = blockIdx.x;
  const float* xr = x + (size_t)t * DIM;
  float acc[NEXP];
  #pragma unroll
  for (int e = 0; e < NEXP; ++e) acc[e] = 0.f;
  for (int d = threadIdx.x; d < DIM; d += 256) {
    float xv = xr[d];
    #pragma unroll
    for (int e = 0; e < NEXP; ++e) acc[e] += xv * gate_w[e * DIM + d];
  }
  #pragma unroll
  for (int e = 0; e < NEXP; ++e) {
    #pragma unroll
    for (int s = 32; s > 0; s >>= 1) acc[e] += __shfl_down(acc[e], s, 64);
  }
  __shared__ float red[4][NEXP];
  const int lane = threadIdx.x & 63, wv = threadIdx.x >> 6;
  if (lane == 0) {
    #pragma unroll
    for (int e = 0; e < NEXP; ++e) red[wv][e] = acc[e];
  }
  __syncthreads();
  if (threadIdx.x == 0) {
    float l[NEXP];
    #pragma unroll
    for (int e = 0; e < NEXP; ++e) l[e] = red[0][e] + red[1][e] + red[2][e] + red[3][e];
    int i0 = 0;
    #pragma unroll
    for (int e = 1; e < NEXP; ++e) if (l[e] > l[i0]) i0 = e;   // lowest index wins ties
    int i1 = (i0 == 0) ? 1 : 0;
    #pragma unroll
    for (int e = 0; e < NEXP; ++e) if (e != i0 && l[e] > l[i1]) i1 = e;
    float w0 = 1.f / (1.f + __expf(l[i1] - l[i0]));   // p0/(p0+p1)
    sel[t * 2] = i0; sel[t * 2 + 1] = i1;
    wgt[t * 2] = w0; wgt[t * 2 + 1] = 1.f - w0;
    atomicAdd(&counts[i0], 1);
    atomicAdd(&counts[i1], 1);
  }
}

__global__ void scan_kernel(const int* __restrict__ counts, int* __restrict__ offs)
{
  if (threadIdx.x == 0) {
    int s = 0;
    for (int e = 0; e < NEXP; ++e) { offs[e] = s; s += counts[e]; }
    offs[NEXP] = s;
  }
}

// ---------------- gather: slot assignment + x -> bf16 segments ----------------
__global__ __launch_bounds__(256) void gather_kernel(
    const float* __restrict__ x, const int* __restrict__ sel, const float* __restrict__ wgt,
    const int* __restrict__ offs, int* __restrict__ fill,
    int* __restrict__ slot_token, float* __restrict__ slot_w,
    int* __restrict__ tok_slots, u16* __restrict__ Xg)
{
  const int id = blockIdx.x;       // t*2 + k
  const int t = id >> 1;
  __shared__ int s_slot;
  if (threadIdx.x == 0) {
    int e = sel[id];
    int pos = atomicAdd(&fill[e], 1);
    int slot = offs[e] + pos;
    s_slot = slot;
    slot_token[slot] = t;
    slot_w[slot] = wgt[id];
    tok_slots[id] = slot;
  }
  __syncthreads();
  const int slot = s_slot;
  const float* src = x + (size_t)t * DIM + threadIdx.x * 8;
  float4 a = *(const float4*)(src);
  float4 b = *(const float4*)(src + 4);
  uint4 o;
  o.x = (u32)f2bf(a.x) | ((u32)f2bf(a.y) << 16);
  o.y = (u32)f2bf(a.z) | ((u32)f2bf(a.w) << 16);
  o.z = (u32)f2bf(b.x) | ((u32)f2bf(b.y) << 16);
  o.w = (u32)f2bf(b.z) | ((u32)f2bf(b.w) << 16);
  *(uint4*)(Xg + (size_t)slot * DIM + threadIdx.x * 8) = o;
}

// ---------------- GEMM1: H = slot_w * silu(Xg@Wg) * (Xg@Wu) ----------------
// BM=128, BN=64, BK=32; double-buffered, single barrier/iter; XOR-swizzled LDS.
__global__ __launch_bounds__(256, 4) void moe_gemm1(
    const u16* __restrict__ Xg,
    const u16* __restrict__ WgT, const u16* __restrict__ WuT,
    const int* __restrict__ offs, const float* __restrict__ slot_w,
    u16* __restrict__ H)
{
  const int e = blockIdx.z;
  const int off = offs[e];
  const int cnt = offs[e + 1] - off;
  const int m0 = blockIdx.y * 128;
  if (m0 >= cnt) return;
  const int n0 = blockIdx.x * 64;

  const u16* __restrict__ Bg_g = WgT + (size_t)e * (size_t)FDIM * DIM;
  const u16* __restrict__ Bu_g = WuT + (size_t)e * (size_t)FDIM * DIM;

  __shared__ __align__(16) u16 As[2][128 * 32];
  __shared__ __align__(16) u16 Bgs[2][64 * 32];
  __shared__ __align__(16) u16 Bus[2][64 * 32];

  const int tid = threadIdx.x;
  const int lane = tid & 63, wave = tid >> 6;
  const int wr = wave >> 1, wc = wave & 1;
  const int quad = lane >> 4, mr = lane & 15;
  // swizzle: LDS chunk c holds global chunk c ^ ((row>>1)&3)
  const int qs   = (((lane & 3) ^ ((lane >> 3) & 3))) * 8;  // staging: global k-chunk for this lane
  const int xorc = ((quad ^ ((mr >> 1) & 3))) * 8;          // fragment read k-chunk

  const u16* agp0 = Xg + (size_t)(off + m0 + wave * 32 + (lane >> 2)) * DIM + qs;
  const u16* agp1 = agp0 + (size_t)16 * DIM;
  const u16* bgp  = Bg_g + (size_t)(n0 + wave * 16 + (lane >> 2)) * DIM + qs;
  const u16* bup  = Bu_g + (size_t)(n0 + wave * 16 + (lane >> 2)) * DIM + qs;
  const int a_lds0 = (wave * 32) * 32;
  const int a_lds1 = (wave * 32 + 16) * 32;
  const int b_lds  = (wave * 16) * 32;

  f32x4 accg[4][2], accu[4][2];
  #pragma unroll
  for (int i = 0; i < 4; ++i)
    #pragma unroll
    for (int j = 0; j < 2; ++j) { accg[i][j] = {0.f,0.f,0.f,0.f}; accu[i][j] = {0.f,0.f,0.f,0.f}; }

  // prologue: stage k0=0 into buffer 0
  gld_lds16(agp0, &As[0][a_lds0]);
  gld_lds16(agp1, &As[0][a_lds1]);
  gld_lds16(bgp,  &Bgs[0][b_lds]);
  gld_lds16(bup,  &Bus[0][b_lds]);

  int p = 0;
  for (int k0 = 0; k0 < DIM; k0 += 32, p ^= 1) {
    __syncthreads();                       // drains buf[p] loads; protects buf[p^1] WAR
    if (k0 + 32 < DIM) {                   // prefetch next slice into buf[p^1]
      gld_lds16(agp0 + k0 + 32, &As[p ^ 1][a_lds0]);
      gld_lds16(agp1 + k0 + 32, &As[p ^ 1][a_lds1]);
      gld_lds16(bgp  + k0 + 32, &Bgs[p ^ 1][b_lds]);
      gld_lds16(bup  + k0 + 32, &Bus[p ^ 1][b_lds]);
    }
    bf16x8 af[4], bgf[2], buf2[2];
    #pragma unroll
    for (int mf = 0; mf < 4; ++mf) {
      B16 t_; t_.u = *(const uint4*)(&As[p][(wr * 64 + mf * 16 + mr) * 32 + xorc]);
      af[mf] = t_.v;
    }
    #pragma unroll
    for (int nf = 0; nf < 2; ++nf) {
      B16 tg; tg.u = *(const uint4*)(&Bgs[p][(wc * 32 + nf * 16 + mr) * 32 + xorc]);
      B16 tu; tu.u = *(const uint4*)(&Bus[p][(wc * 32 + nf * 16 + mr) * 32 + xorc]);
      bgf[nf] = tg.v; buf2[nf] = tu.v;
    }
    #pragma unroll
    for (int nf = 0; nf < 2; ++nf)
      #pragma unroll
      for (int mf = 0; mf < 4; ++mf) {
        accg[mf][nf] = __builtin_amdgcn_mfma_f32_16x16x32_bf16(af[mf], bgf[nf],  accg[mf][nf], 0, 0, 0);
        accu[mf][nf] = __builtin_amdgcn_mfma_f32_16x16x32_bf16(af[mf], buf2[nf], accu[mf][nf], 0, 0, 0);
      }
  }

  #pragma unroll
  for (int mf = 0; mf < 4; ++mf) {
    #pragma unroll
    for (int r = 0; r < 4; ++r) {
      int row = wr * 64 + mf * 16 + quad * 4 + r;
      if (m0 + row < cnt) {
        int slot = off + m0 + row;
        float w = slot_w[slot];
        #pragma unroll
        for (int nf = 0; nf < 2; ++nf) {
          float g = accg[mf][nf][r];
          float u = accu[mf][nf][r];
          float s = g / (1.f + __expf(-g));
          H[(size_t)slot * FDIM + n0 + wc * 32 + nf * 16 + mr] = f2bf(w * s * u);
        }
      }
    }
  }
}

// ---------------- GEMM2: Ho[slot] = H[slot] @ Wd ----------------
__global__ __launch_bounds__(256, 4) void moe_gemm2(
    const u16* __restrict__ H, const u16* __restrict__ WdT,
    const int* __restrict__ offs, u16* __restrict__ Ho)
{
  const int e = blockIdx.z;
  const int off = offs[e];
  const int cnt = offs[e + 1] - off;
  const int m0 = blockIdx.y * 128;
  if (m0 >= cnt) return;
  const int n0 = blockIdx.x * 64;

  const u16* __restrict__ Bd_g = WdT + (size_t)e * (size_t)DIM * FDIM;  // [d][f]

  __shared__ __align__(16) u16 As[2][128 * 32];
  __shared__ __align__(16) u16 Bds[2][64 * 32];

  const int tid = threadIdx.x;
  const int lane = tid & 63, wave = tid >> 6;
  const int wr = wave >> 1, wc = wave & 1;
  const int quad = lane >> 4, mr = lane & 15;
  const int qs   = (((lane & 3) ^ ((lane >> 3) & 3))) * 8;
  const int xorc = ((quad ^ ((mr >> 1) & 3))) * 8;

  const u16* agp0 = H + (size_t)(off + m0 + wave * 32 + (lane >> 2)) * FDIM + qs;
  const u16* agp1 = agp0 + (size_t)16 * FDIM;
  const u16* bdp  = Bd_g + (size_t)(n0 + wave * 16 + (lane >> 2)) * FDIM + qs;
  const int a_lds0 = (wave * 32) * 32;
  const int a_lds1 = (wave * 32 + 16) * 32;
  const int b_lds  = (wave * 16) * 32;

  f32x4 acc[4][2];
  #pragma unroll
  for (int i = 0; i < 4; ++i)
    #pragma unroll
    for (int j = 0; j < 2; ++j) acc[i][j] = {0.f,0.f,0.f,0.f};

  gld_lds16(agp0, &As[0][a_lds0]);
  gld_lds16(agp1, &As[0][a_lds1]);
  gld_lds16(bdp,  &Bds[0][b_lds]);

  int p = 0;
  for (int k0 = 0; k0 < FDIM; k0 += 32, p ^= 1) {
    __syncthreads();
    if (k0 + 32 < FDIM) {
      gld_lds16(agp0 + k0 + 32, &As[p ^ 1][a_lds0]);
      gld_lds16(agp1 + k0 + 32, &As[p ^ 1][a_lds1]);
      gld_lds16(bdp  + k0 + 32, &Bds[p ^ 1][b_lds]);
    }
    bf16x8 af[4], bdf[2];
    #pragma unroll
    for (int mf = 0; mf < 4; ++mf) {
      B16 t_; t_.u = *(const uint4*)(&As[p][(wr * 64 + mf * 16 + mr) * 32 + xorc]);
      af[mf] = t_.v;
    }
    #pragma unroll
    for (int nf = 0; nf < 2; ++nf) {
      B16 tb; tb.u = *(const uint4*)(&Bds[p][(wc * 32 + nf * 16 + mr) * 32 + xorc]);
      bdf[nf] = tb.v;
    }
    #pragma unroll
    for (int nf = 0; nf < 2; ++nf)
      #pragma unroll
      for (int mf = 0; mf < 4; ++mf)
        acc[mf][nf] = __builtin_amdgcn_mfma_f32_16x16x32_bf16(af[mf], bdf[nf], acc[mf][nf], 0, 0, 0);
  }

  #pragma unroll
  for (int mf = 0; mf < 4; ++mf) {
    #pragma unroll
    for (int r = 0; r < 4; ++r) {
      int row = wr * 64 + mf * 16 + quad * 4 + r;
      if (m0 + row < cnt) {
        int slot = off + m0 + row;
        #pragma unroll
        for (int nf = 0; nf < 2; ++nf)
          Ho[(size_t)slot * DIM + n0 + wc * 32 + nf * 16 + mr] = f2bf(acc[mf][nf][r]);
      }
    }
  }
}

// ---------------- combine: out[t] = Ho[slot0(t)] + Ho[slot1(t)] ----------------
__global__ __launch_bounds__(256) void combine_kernel(
    const u16* __restrict__ Ho, const int* __restrict__ tok_slots,
    float* __restrict__ out)
{
  const int t = blockIdx.x;
  const int s0 = tok_slots[t * 2], s1 = tok_slots[t * 2 + 1];
  const int base = threadIdx.x * 8;
  uint4 a = *(const uint4*)(Ho + (size_t)s0 * DIM + base);
  uint4 b = *(const uint4*)(Ho + (size_t)s1 * DIM + base);
  float* o = out + (size_t)t * DIM + base;
  float4 lo, hi;
  lo.x = bf2f((u16)(a.x & 0xFFFF)) + bf2f((u16)(b.x & 0xFFFF));
  lo.y = bf2f((u16)(a.x >> 16))    + bf2f((u16)(b.x >> 16));
  lo.z = bf2f((u16)(a.y & 0xFFFF)) + bf2f((u16)(b.y & 0xFFFF));
  lo.w = bf2f((u16)(a.y >> 16))    + bf2f((u16)(b.y >> 16));
  hi.x = bf2f((u16)(a.z & 0xFFFF)) + bf2f((u16)(b.z & 0xFFFF));
  hi.y = bf2f((u16)(a.z >> 16))    + bf2f((u16)(b.z >> 16));
  hi.z = bf2f((u16)(a.w & 0xFFFF)) + bf2f((u16)(b.w & 0xFFFF));
  hi.w = bf2f((u16)(a.w >> 16))    + bf2f((u16)(b.w >> 16));
  *(float4*)(o)     = lo;
  *(float4*)(o + 4) = hi;
}

extern "C" void kernel_launch(void* const* d_in, const int* in_sizes, int n_in,
                              void* d_out, int out_size, void* d_ws, size_t ws_size,
                              hipStream_t stream) {
  const float* x      = (const float*)d_in[0];
  const float* gate_w = (const float*)d_in[1];
  const float* w_gate = (const float*)d_in[2];
  const float* w_up   = (const float*)d_in[3];
  const float* w_down = (const float*)d_in[4];
  float* out = (float*)d_out;

  char* w = (char*)d_ws;
  int*   counts     = (int*)(w + 0);
  int*   fill       = (int*)(w + 64);
  int*   offs       = (int*)(w + 128);
  int*   sel        = (int*)(w + 4096);
  float* wgt        = (float*)(w + 4096 + 16384);
  int*   tok_slots  = (int*)(w + 4096 + 2 * 16384);
  int*   slot_token = (int*)(w + 4096 + 3 * 16384);
  float* slot_w     = (float*)(w + 4096 + 3 * 16384 + 17408);
  size_t o = 131072;
  u16* Xg  = (u16*)(w + o); o += (size_t)SLOTS * DIM  * 2;   // 17.3 MB
  u16* H   = (u16*)(w + o); o += (size_t)SLOTS * FDIM * 2;   // 11.9 MB
  u16* Ho  = (u16*)(w + o); o += (size_t)SLOTS * DIM  * 2;   // 17.3 MB
  u16* WgT = (u16*)(w + o); o += (size_t)NEXP * DIM * FDIM * 2;  // 46.1 MB
  u16* WuT = (u16*)(w + o); o += (size_t)NEXP * DIM * FDIM * 2;
  u16* WdT = (u16*)(w + o); o += (size_t)NEXP * DIM * FDIM * 2;

  hipMemsetAsync(d_ws, 0, 256, stream);   // counts + fill

  dim3 gc(32, 32, 24);
  cvt_transpose<<<gc, 256, 0, stream>>>(w_gate, w_up, w_down, WgT, WuT, WdT);

  router_kernel<<<T_TOK, 256, 0, stream>>>(x, gate_w, sel, wgt, counts);
  scan_kernel<<<1, 64, 0, stream>>>(counts, offs);
  gather_kernel<<<T_TOK * 2, 256, 0, stream>>>(x, sel, wgt, offs, fill,
                                               slot_token, slot_w, tok_slots, Xg);

  dim3 g1(FDIM / 64, 16, NEXP);   // max cnt/expert = 2048 -> 16 m-tiles
  moe_gemm1<<<g1, 256, 0, stream>>>(Xg, WgT, WuT, offs, slot_w, H);

  dim3 g2(DIM / 64, 16, NEXP);
  moe_gemm2<<<g2, 256, 0, stream>>>(H, WdT, offs, Ho);

  combine_kernel<<<T_TOK, 256, 0, stream>>>(Ho, tok_slots, out);
}

// Round 4
// 563.160 us; speedup vs baseline: 1.0220x; 1.0220x over previous
//
#include <hip/hip_runtime.h>

typedef unsigned short u16;
typedef unsigned int   u32;

#define T_TOK 2048
#define DIM   2048
#define FDIM  1408
#define NEXP  8
#define SLOTS 4224   // 4096 + 128 tail headroom

typedef __bf16 bf16x8 __attribute__((ext_vector_type(8)));
typedef float  f32x4  __attribute__((ext_vector_type(4)));

union B16 { uint4 u; bf16x8 v; };

__device__ __forceinline__ u16 f2bf(float f) {
  union { float f; u32 u; } c; c.f = f;
  u32 u = c.u;
  u += 0x7FFFu + ((u >> 16) & 1u);   // round-to-nearest-even
  return (u16)(u >> 16);
}
__device__ __forceinline__ float bf2f(u16 h) {
  union { u32 u; float f; } c; c.u = (u32)h << 16; return c.f;
}

// async global->LDS, 16B per lane; lds base wave-uniform, lane i lands at base + i*16
__device__ __forceinline__ void gld_lds16(const void* g, void* l) {
  __builtin_amdgcn_global_load_lds(
      (const __attribute__((address_space(1))) unsigned int*)g,
      (__attribute__((address_space(3))) unsigned int*)l, 16, 0, 0);
}

// ---------------- weight cvt fp32->bf16 + transpose [K][N] -> [N][K] ----------------
__global__ __launch_bounds__(256) void cvt_transpose(
    const float* __restrict__ Wg, const float* __restrict__ Wu, const float* __restrict__ Wd,
    u16* __restrict__ WgT, u16* __restrict__ WuT, u16* __restrict__ WdT)
{
  const int z = blockIdx.z;
  const int tensor = z >> 3;
  const int e = z & 7;
  const int Kt = (tensor == 2) ? FDIM : DIM;
  const int Nt = (tensor == 2) ? DIM : FDIM;
  const float* src;
  u16* dst;
  if (tensor == 0)      { src = Wg + (size_t)e * DIM * FDIM; dst = WgT + (size_t)e * DIM * FDIM; }
  else if (tensor == 1) { src = Wu + (size_t)e * DIM * FDIM; dst = WuT + (size_t)e * DIM * FDIM; }
  else                  { src = Wd + (size_t)e * DIM * FDIM; dst = WdT + (size_t)e * DIM * FDIM; }
  const int k0 = blockIdx.y * 64, n0 = blockIdx.x * 64;
  if (k0 >= Kt || n0 >= Nt) return;

  __shared__ u16 tile[64][68];   // +4 pad
  const int tid = threadIdx.x;
  #pragma unroll
  for (int p = 0; p < 4; ++p) {                      // coalesced fp32 reads, 16 k-rows/pass
    int k = p * 16 + (tid >> 4);
    int n = (tid & 15) * 4;
    float4 v = *(const float4*)(src + (size_t)(k0 + k) * Nt + n0 + n);
    uint2 o;
    o.x = (u32)f2bf(v.x) | ((u32)f2bf(v.y) << 16);
    o.y = (u32)f2bf(v.z) | ((u32)f2bf(v.w) << 16);
    *(uint2*)(&tile[k][n]) = o;
  }
  __syncthreads();
  // write phase: 16B per lane, 8 n-rows x 128B contiguous per wave
  #pragma unroll
  for (int p = 0; p < 2; ++p) {
    int n  = p * 32 + (tid >> 3);
    int kc = (tid & 7) * 8;
    u16 r[8];
    #pragma unroll
    for (int j = 0; j < 8; ++j) r[j] = tile[kc + j][n];
    uint4 o;
    o.x = (u32)r[0] | ((u32)r[1] << 16);
    o.y = (u32)r[2] | ((u32)r[3] << 16);
    o.z = (u32)r[4] | ((u32)r[5] << 16);
    o.w = (u32)r[6] | ((u32)r[7] << 16);
    *(uint4*)(dst + (size_t)(n0 + n) * Kt + k0 + kc) = o;
  }
}

// ---------------- router: fp32 logits, softmax top-2 renormalized ----------------
__global__ __launch_bounds__(256) void router_kernel(
    const float* __restrict__ x, const float* __restrict__ gate_w,
    int* __restrict__ sel, float* __restrict__ wgt, int* __restrict__ counts)
{
  const int t = blockIdx.x;
  const float* xr = x + (size_t)t * DIM;
  float acc[NEXP];
  #pragma unroll
  for (int e = 0; e < NEXP; ++e) acc[e] = 0.f;
  for (int d = threadIdx.x; d < DIM; d += 256) {
    float xv = xr[d];
    #pragma unroll
    for (int e = 0; e < NEXP; ++e) acc[e] += xv * gate_w[e * DIM + d];
  }
  #pragma unroll
  for (int e = 0; e < NEXP; ++e) {
    #pragma unroll
    for (int s = 32; s > 0; s >>= 1) acc[e] += __shfl_down(acc[e], s, 64);
  }
  __shared__ float red[4][NEXP];
  const int lane = threadIdx.x & 63, wv = threadIdx.x >> 6;
  if (lane == 0) {
    #pragma unroll
    for (int e = 0; e < NEXP; ++e) red[wv][e] = acc[e];
  }
  __syncthreads();
  if (threadIdx.x == 0) {
    float l[NEXP];
    #pragma unroll
    for (int e = 0; e < NEXP; ++e) l[e] = red[0][e] + red[1][e] + red[2][e] + red[3][e];
    int i0 = 0;
    #pragma unroll
    for (int e = 1; e < NEXP; ++e) if (l[e] > l[i0]) i0 = e;   // lowest index wins ties
    int i1 = (i0 == 0) ? 1 : 0;
    #pragma unroll
    for (int e = 0; e < NEXP; ++e) if (e != i0 && l[e] > l[i1]) i1 = e;
    float w0 = 1.f / (1.f + __expf(l[i1] - l[i0]));   // p0/(p0+p1)
    sel[t * 2] = i0; sel[t * 2 + 1] = i1;
    wgt[t * 2] = w0; wgt[t * 2 + 1] = 1.f - w0;
    atomicAdd(&counts[i0], 1);
    atomicAdd(&counts[i1], 1);
  }
}

__global__ void scan_kernel(const int* __restrict__ counts, int* __restrict__ offs)
{
  if (threadIdx.x == 0) {
    int s = 0;
    for (int e = 0; e < NEXP; ++e) { offs[e] = s; s += counts[e]; }
    offs[NEXP] = s;
  }
}

// ---------------- gather: slot assignment + x -> bf16 segments ----------------
__global__ __launch_bounds__(256) void gather_kernel(
    const float* __restrict__ x, const int* __restrict__ sel, const float* __restrict__ wgt,
    const int* __restrict__ offs, int* __restrict__ fill,
    int* __restrict__ slot_token, float* __restrict__ slot_w,
    int* __restrict__ tok_slots, u16* __restrict__ Xg)
{
  const int id = blockIdx.x;       // t*2 + k
  const int t = id >> 1;
  __shared__ int s_slot;
  if (threadIdx.x == 0) {
    int e = sel[id];
    int pos = atomicAdd(&fill[e], 1);
    int slot = offs[e] + pos;
    s_slot = slot;
    slot_token[slot] = t;
    slot_w[slot] = wgt[id];
    tok_slots[id] = slot;
  }
  __syncthreads();
  const int slot = s_slot;
  const float* src = x + (size_t)t * DIM + threadIdx.x * 8;
  float4 a = *(const float4*)(src);
  float4 b = *(const float4*)(src + 4);
  uint4 o;
  o.x = (u32)f2bf(a.x) | ((u32)f2bf(a.y) << 16);
  o.y = (u32)f2bf(a.z) | ((u32)f2bf(a.w) << 16);
  o.z = (u32)f2bf(b.x) | ((u32)f2bf(b.y) << 16);
  o.w = (u32)f2bf(b.z) | ((u32)f2bf(b.w) << 16);
  *(uint4*)(Xg + (size_t)slot * DIM + threadIdx.x * 8) = o;
}

// ---------------- GEMM1: H = slot_w * silu(Xg@Wg) * (Xg@Wu) ----------------
// BM=128, BN=64, BK=64 (full 128B lines); single-buffer; XCD-grouped 1D grid.
// Swizzle: LDS chunk c holds global chunk c ^ (row&7); staging lanes permute
// chunks within one 128B line so global reads stay fully coalesced.
__global__ __launch_bounds__(256, 4) void moe_gemm1(
    const u16* __restrict__ Xg,
    const u16* __restrict__ WgT, const u16* __restrict__ WuT,
    const int* __restrict__ offs, const float* __restrict__ slot_w,
    u16* __restrict__ H)
{
  const int id  = blockIdx.x;
  const int xcd = id & 7;
  const int j   = id >> 3;
  const int mt  = j & 15;          // m-tile, innermost -> same-(e,n) blocks adjacent & same XCD
  const int j2  = j >> 4;
  const int e   = j2 & 7;
  const int ni  = j2 >> 3;         // 0..2
  const int nt  = xcd + 8 * ni;    // n-tile
  if (nt >= FDIM / 64) return;

  const int off = offs[e];
  const int cnt = offs[e + 1] - off;
  const int m0 = mt * 128;
  if (m0 >= cnt) return;
  const int n0 = nt * 64;

  const u16* __restrict__ Bg_g = WgT + (size_t)e * (size_t)FDIM * DIM;
  const u16* __restrict__ Bu_g = WuT + (size_t)e * (size_t)FDIM * DIM;

  __shared__ __align__(16) u16 As[128 * 64];   // 16 KB
  __shared__ __align__(16) u16 Bgs[64 * 64];   // 8 KB
  __shared__ __align__(16) u16 Bus[64 * 64];   // 8 KB

  const int tid = threadIdx.x;
  const int lane = tid & 63, wave = tid >> 6;
  const int wr = wave >> 1, wc = wave & 1;
  const int quad = lane >> 4, mr = lane & 15;
  const int r8 = lane >> 3;                    // row within 8-row staging group
  const int cs = ((lane & 7) ^ (r8 & 7)) * 8;  // swizzled source chunk (elems) within 128B line

  // staging pointers (advance by k0 elems per iter)
  const u16* a_base  = Xg   + (size_t)(off + m0 + wave * 32 + r8) * DIM + cs;
  const u16* bg_base = Bg_g + (size_t)(n0 + wave * 16 + r8) * DIM + cs;
  const u16* bu_base = Bu_g + (size_t)(n0 + wave * 16 + r8) * DIM + cs;

  f32x4 accg[4][2], accu[4][2];
  #pragma unroll
  for (int i = 0; i < 4; ++i)
    #pragma unroll
    for (int jj = 0; jj < 2; ++jj) { accg[i][jj] = {0.f,0.f,0.f,0.f}; accu[i][jj] = {0.f,0.f,0.f,0.f}; }

  for (int k0 = 0; k0 < DIM; k0 += 64) {
    #pragma unroll
    for (int g = 0; g < 4; ++g)    // A: 32 rows per wave, 8 rows per load
      gld_lds16(a_base + (size_t)g * 8 * DIM + k0, &As[(wave * 32 + g * 8) * 64]);
    #pragma unroll
    for (int g = 0; g < 2; ++g) {  // B: 16 rows per wave per tensor
      gld_lds16(bg_base + (size_t)g * 8 * DIM + k0, &Bgs[(wave * 16 + g * 8) * 64]);
      gld_lds16(bu_base + (size_t)g * 8 * DIM + k0, &Bus[(wave * 16 + g * 8) * 64]);
    }
    __syncthreads();
    #pragma unroll
    for (int s = 0; s < 2; ++s) {
      const int ca = ((4 * s + quad) ^ (mr & 7)) * 8;  // swizzled chunk for frag reads
      bf16x8 af[4], bgf[2], buf2[2];
      #pragma unroll
      for (int mf = 0; mf < 4; ++mf) {
        B16 t_; t_.u = *(const uint4*)(&As[(wr * 64 + mf * 16 + mr) * 64 + ca]);
        af[mf] = t_.v;
      }
      #pragma unroll
      for (int nf = 0; nf < 2; ++nf) {
        B16 tg; tg.u = *(const uint4*)(&Bgs[(wc * 32 + nf * 16 + mr) * 64 + ca]);
        B16 tu; tu.u = *(const uint4*)(&Bus[(wc * 32 + nf * 16 + mr) * 64 + ca]);
        bgf[nf] = tg.v; buf2[nf] = tu.v;
      }
      #pragma unroll
      for (int nf = 0; nf < 2; ++nf)
        #pragma unroll
        for (int mf = 0; mf < 4; ++mf) {
          accg[mf][nf] = __builtin_amdgcn_mfma_f32_16x16x32_bf16(af[mf], bgf[nf],  accg[mf][nf], 0, 0, 0);
          accu[mf][nf] = __builtin_amdgcn_mfma_f32_16x16x32_bf16(af[mf], buf2[nf], accu[mf][nf], 0, 0, 0);
        }
    }
    __syncthreads();
  }

  #pragma unroll
  for (int mf = 0; mf < 4; ++mf) {
    #pragma unroll
    for (int r = 0; r < 4; ++r) {
      int row = wr * 64 + mf * 16 + quad * 4 + r;
      if (m0 + row < cnt) {
        int slot = off + m0 + row;
        float w = slot_w[slot];
        #pragma unroll
        for (int nf = 0; nf < 2; ++nf) {
          float g = accg[mf][nf][r];
          float u = accu[mf][nf][r];
          float s = g / (1.f + __expf(-g));
          H[(size_t)slot * FDIM + n0 + wc * 32 + nf * 16 + mr] = f2bf(w * s * u);
        }
      }
    }
  }
}

// ---------------- GEMM2: Ho[slot] = H[slot] @ Wd ----------------
__global__ __launch_bounds__(256, 4) void moe_gemm2(
    const u16* __restrict__ H, const u16* __restrict__ WdT,
    const int* __restrict__ offs, u16* __restrict__ Ho)
{
  const int id  = blockIdx.x;
  const int xcd = id & 7;
  const int j   = id >> 3;
  const int mt  = j & 15;
  const int j2  = j >> 4;
  const int e   = j2 & 7;
  const int ni  = j2 >> 3;         // 0..3
  const int nt  = xcd + 8 * ni;    // 0..31

  const int off = offs[e];
  const int cnt = offs[e + 1] - off;
  const int m0 = mt * 128;
  if (m0 >= cnt) return;
  const int n0 = nt * 64;

  const u16* __restrict__ Bd_g = WdT + (size_t)e * (size_t)DIM * FDIM;  // [d][f]

  __shared__ __align__(16) u16 As[128 * 64];   // 16 KB
  __shared__ __align__(16) u16 Bds[64 * 64];   // 8 KB

  const int tid = threadIdx.x;
  const int lane = tid & 63, wave = tid >> 6;
  const int wr = wave >> 1, wc = wave & 1;
  const int quad = lane >> 4, mr = lane & 15;
  const int r8 = lane >> 3;
  const int cs = ((lane & 7) ^ (r8 & 7)) * 8;

  const u16* a_base  = H    + (size_t)(off + m0 + wave * 32 + r8) * FDIM + cs;
  const u16* bd_base = Bd_g + (size_t)(n0 + wave * 16 + r8) * FDIM + cs;

  f32x4 acc[4][2];
  #pragma unroll
  for (int i = 0; i < 4; ++i)
    #pragma unroll
    for (int jj = 0; jj < 2; ++jj) acc[i][jj] = {0.f,0.f,0.f,0.f};

  for (int k0 = 0; k0 < FDIM; k0 += 64) {
    #pragma unroll
    for (int g = 0; g < 4; ++g)
      gld_lds16(a_base + (size_t)g * 8 * FDIM + k0, &As[(wave * 32 + g * 8) * 64]);
    #pragma unroll
    for (int g = 0; g < 2; ++g)
      gld_lds16(bd_base + (size_t)g * 8 * FDIM + k0, &Bds[(wave * 16 + g * 8) * 64]);
    __syncthreads();
    #pragma unroll
    for (int s = 0; s < 2; ++s) {
      const int ca = ((4 * s + quad) ^ (mr & 7)) * 8;
      bf16x8 af[4], bdf[2];
      #pragma unroll
      for (int mf = 0; mf < 4; ++mf) {
        B16 t_; t_.u = *(const uint4*)(&As[(wr * 64 + mf * 16 + mr) * 64 + ca]);
        af[mf] = t_.v;
      }
      #pragma unroll
      for (int nf = 0; nf < 2; ++nf) {
        B16 tb; tb.u = *(const uint4*)(&Bds[(wc * 32 + nf * 16 + mr) * 64 + ca]);
        bdf[nf] = tb.v;
      }
      #pragma unroll
      for (int nf = 0; nf < 2; ++nf)
        #pragma unroll
        for (int mf = 0; mf < 4; ++mf)
          acc[mf][nf] = __builtin_amdgcn_mfma_f32_16x16x32_bf16(af[mf], bdf[nf], acc[mf][nf], 0, 0, 0);
    }
    __syncthreads();
  }

  #pragma unroll
  for (int mf = 0; mf < 4; ++mf) {
    #pragma unroll
    for (int r = 0; r < 4; ++r) {
      int row = wr * 64 + mf * 16 + quad * 4 + r;
      if (m0 + row < cnt) {
        int slot = off + m0 + row;
        #pragma unroll
        for (int nf = 0; nf < 2; ++nf)
          Ho[(size_t)slot * DIM + n0 + wc * 32 + nf * 16 + mr] = f2bf(acc[mf][nf][r]);
      }
    }
  }
}

// ---------------- combine: out[t] = Ho[slot0(t)] + Ho[slot1(t)] ----------------
__global__ __launch_bounds__(256) void combine_kernel(
    const u16* __restrict__ Ho, const int* __restrict__ tok_slots,
    float* __restrict__ out)
{
  const int t = blockIdx.x;
  const int s0 = tok_slots[t * 2], s1 = tok_slots[t * 2 + 1];
  const int base = threadIdx.x * 8;
  uint4 a = *(const uint4*)(Ho + (size_t)s0 * DIM + base);
  uint4 b = *(const uint4*)(Ho + (size_t)s1 * DIM + base);
  float* o = out + (size_t)t * DIM + base;
  float4 lo, hi;
  lo.x = bf2f((u16)(a.x & 0xFFFF)) + bf2f((u16)(b.x & 0xFFFF));
  lo.y = bf2f((u16)(a.x >> 16))    + bf2f((u16)(b.x >> 16));
  lo.z = bf2f((u16)(a.y & 0xFFFF)) + bf2f((u16)(b.y & 0xFFFF));
  lo.w = bf2f((u16)(a.y >> 16))    + bf2f((u16)(b.y >> 16));
  hi.x = bf2f((u16)(a.z & 0xFFFF)) + bf2f((u16)(b.z & 0xFFFF));
  hi.y = bf2f((u16)(a.z >> 16))    + bf2f((u16)(b.z >> 16));
  hi.z = bf2f((u16)(a.w & 0xFFFF)) + bf2f((u16)(b.w & 0xFFFF));
  hi.w = bf2f((u16)(a.w >> 16))    + bf2f((u16)(b.w >> 16));
  *(float4*)(o)     = lo;
  *(float4*)(o + 4) = hi;
}

extern "C" void kernel_launch(void* const* d_in, const int* in_sizes, int n_in,
                              void* d_out, int out_size, void* d_ws, size_t ws_size,
                              hipStream_t stream) {
  const float* x      = (const float*)d_in[0];
  const float* gate_w = (const float*)d_in[1];
  const float* w_gate = (const float*)d_in[2];
  const float* w_up   = (const float*)d_in[3];
  const float* w_down = (const float*)d_in[4];
  float* out = (float*)d_out;

  char* w = (char*)d_ws;
  int*   counts     = (int*)(w + 0);
  int*   fill       = (int*)(w + 64);
  int*   offs       = (int*)(w + 128);
  int*   sel        = (int*)(w + 4096);
  float* wgt        = (float*)(w + 4096 + 16384);
  int*   tok_slots  = (int*)(w + 4096 + 2 * 16384);
  int*   slot_token = (int*)(w + 4096 + 3 * 16384);
  float* slot_w     = (float*)(w + 4096 + 3 * 16384 + 17408);
  size_t o = 131072;
  u16* Xg  = (u16*)(w + o); o += (size_t)SLOTS * DIM  * 2;   // 17.3 MB
  u16* H   = (u16*)(w + o); o += (size_t)SLOTS * FDIM * 2;   // 11.9 MB
  u16* Ho  = (u16*)(w + o); o += (size_t)SLOTS * DIM  * 2;   // 17.3 MB
  u16* WgT = (u16*)(w + o); o += (size_t)NEXP * DIM * FDIM * 2;  // 46.1 MB
  u16* WuT = (u16*)(w + o); o += (size_t)NEXP * DIM * FDIM * 2;
  u16* WdT = (u16*)(w + o); o += (size_t)NEXP * DIM * FDIM * 2;

  hipMemsetAsync(d_ws, 0, 256, stream);   // counts + fill

  dim3 gc(32, 32, 24);
  cvt_transpose<<<gc, 256, 0, stream>>>(w_gate, w_up, w_down, WgT, WuT, WdT);

  router_kernel<<<T_TOK, 256, 0, stream>>>(x, gate_w, sel, wgt, counts);
  scan_kernel<<<1, 64, 0, stream>>>(counts, offs);
  gather_kernel<<<T_TOK * 2, 256, 0, stream>>>(x, sel, wgt, offs, fill,
                                               slot_token, slot_w, tok_slots, Xg);

  // XCD-grouped 1D grids: id%8 = XCD, m-tile innermost (same-(e,n) blocks adjacent)
  moe_gemm1<<<8 * 16 * 8 * 3, 256, 0, stream>>>(Xg, WgT, WuT, offs, slot_w, H);
  moe_gemm2<<<8 * 16 * 8 * 4, 256, 0, stream>>>(H, WdT, offs, Ho);

  combine_kernel<<<T_TOK, 256, 0, stream>>>(Ho, tok_slots, out);
}